// Round 2
// baseline (608.656 us; speedup 1.0000x reference)
//
#include <hip/hip_runtime.h>

#define N_NODES 50000
#define N_EDGES 500000
#define F_DIM 256
#define ED_DIM 64
#define H_DIM 128
#define O_DIM 32
#define NEG_SLOPE 0.2f
#define EPS_F 1e-16f

// ---------------- we_vec = We @ a_edge (both layers) ----------------
__global__ void k_wevec(const float* __restrict__ We1, const float* __restrict__ aev1,
                        const float* __restrict__ We2, const float* __restrict__ aev2,
                        float* __restrict__ wv1, float* __restrict__ wv2) {
    int t = threadIdx.x;
    if (t < 64) {
        float s = 0.f;
        for (int c = 0; c < H_DIM; c++) s += We1[t * H_DIM + c] * aev1[c];
        wv1[t] = s;
    } else {
        int k = t - 64;
        float s = 0.f;
        for (int c = 0; c < O_DIM; c++) s += We2[k * O_DIM + c] * aev2[c];
        wv2[k] = s;
    }
}

// ------------- per-edge a_e (both layers) + degree histogram -------------
__global__ void k_edge_ae(const float* __restrict__ ea, const int* __restrict__ dst,
                          const float* __restrict__ wv1, const float* __restrict__ wv2,
                          float* __restrict__ ae1, float* __restrict__ ae2,
                          float* __restrict__ aesum1, float* __restrict__ aesum2,
                          int* __restrict__ cnt) {
    int e = blockIdx.x * blockDim.x + threadIdx.x;
    if (e >= N_EDGES) return;
    const float4* row = (const float4*)(ea + (size_t)e * ED_DIM);
    float s1 = 0.f, s2 = 0.f;
#pragma unroll
    for (int j = 0; j < ED_DIM / 4; j++) {
        float4 q = row[j];
        int k = j * 4;
        s1 += q.x * wv1[k] + q.y * wv1[k + 1] + q.z * wv1[k + 2] + q.w * wv1[k + 3];
        s2 += q.x * wv2[k] + q.y * wv2[k + 1] + q.z * wv2[k + 2] + q.w * wv2[k + 3];
    }
    ae1[e] = s1; ae2[e] = s2;
    int d = dst[e];
    atomicAdd(&aesum1[d], s1);
    atomicAdd(&aesum2[d], s2);
    atomicAdd(&cnt[d], 1);
}

// ---------------- prefix-sum (CSR offsets), 3 kernels ----------------
__global__ void k_scan1(const int* __restrict__ cnt, int* __restrict__ bsum, int n) {
    __shared__ int sh[256];
    int b = blockIdx.x, t = threadIdx.x;
    int base = b * 1024;
    int s = 0;
    for (int j = 0; j < 4; j++) {
        int idx = base + t * 4 + j;
        if (idx < n) s += cnt[idx];
    }
    sh[t] = s; __syncthreads();
    for (int o = 128; o > 0; o >>= 1) {
        if (t < o) sh[t] += sh[t + o];
        __syncthreads();
    }
    if (t == 0) bsum[b] = sh[0];
}

__global__ void k_scan2(const int* __restrict__ bsum, int* __restrict__ bpre,
                        int* __restrict__ offs, int nb, int n) {
    if (threadIdx.x == 0) {
        int run = 0;
        for (int b = 0; b < nb; b++) { bpre[b] = run; run += bsum[b]; }
        offs[n] = run;
    }
}

__global__ void k_scan3(const int* __restrict__ cnt, const int* __restrict__ bpre,
                        int* __restrict__ offs, int n) {
    __shared__ int sh[256];
    int b = blockIdx.x, t = threadIdx.x;
    int base = b * 1024;
    int v[4]; int s = 0;
    for (int j = 0; j < 4; j++) {
        int idx = base + t * 4 + j;
        v[j] = (idx < n) ? cnt[idx] : 0;
        s += v[j];
    }
    sh[t] = s; __syncthreads();
    for (int o = 1; o < 256; o <<= 1) {
        int x = (t >= o) ? sh[t - o] : 0;
        __syncthreads();
        sh[t] += x;
        __syncthreads();
    }
    int texcl = sh[t] - s + bpre[b];
    int run = 0;
    for (int j = 0; j < 4; j++) {
        int idx = base + t * 4 + j;
        if (idx < n) offs[idx] = texcl + run;
        run += v[j];
    }
}

__global__ void k_scatter(const int* __restrict__ src, const int* __restrict__ dst,
                          int* __restrict__ cursor,
                          int* __restrict__ csr_src, int* __restrict__ csr_eid) {
    int e = blockIdx.x * blockDim.x + threadIdx.x;
    if (e >= N_EDGES) return;
    int d = dst[e];
    int p = atomicAdd(&cursor[d], 1);
    csr_src[p] = src[e];
    csr_eid[p] = e;
}

// ---------------- tiled GEMM: C(MxN) = A(MxK) @ B(KxN), fp32 ----------------
template <int BM, int BN, int BK, int TM, int TN>
__global__ void k_gemm(const float* __restrict__ A, const float* __restrict__ B,
                       float* __restrict__ C, int M, int N, int K) {
    constexpr int NT = (BM / TM) * (BN / TN);
    __shared__ float As[BK][BM + 1];
    __shared__ float Bs[BK][BN + 1];
    int tid = threadIdx.x;
    int bm0 = blockIdx.x * BM, bn0 = blockIdx.y * BN;
    int ty = tid / (BN / TN), tx = tid % (BN / TN);
    float acc[TM][TN] = {};
    for (int k0 = 0; k0 < K; k0 += BK) {
        for (int i = tid; i < BM * BK; i += NT) {
            int m = i / BK, k = i % BK;
            int gm = bm0 + m;
            As[k][m] = (gm < M) ? A[(size_t)gm * K + k0 + k] : 0.f;
        }
        for (int i = tid; i < BK * BN; i += NT) {
            int k = i / BN, n = i % BN;
            Bs[k][n] = B[(size_t)(k0 + k) * N + bn0 + n];
        }
        __syncthreads();
#pragma unroll
        for (int k = 0; k < BK; k++) {
            float a[TM], bb[TN];
#pragma unroll
            for (int i = 0; i < TM; i++) a[i] = As[k][ty * TM + i];
#pragma unroll
            for (int j = 0; j < TN; j++) bb[j] = Bs[k][tx * TN + j];
#pragma unroll
            for (int i = 0; i < TM; i++)
#pragma unroll
                for (int j = 0; j < TN; j++) acc[i][j] += a[i] * bb[j];
        }
        __syncthreads();
    }
    for (int i = 0; i < TM; i++) {
        int gm = bm0 + ty * TM + i;
        if (gm >= M) continue;
        for (int j = 0; j < TN; j++)
            C[(size_t)gm * N + bn0 + tx * TN + j] = acc[i][j];
    }
}

// ---------------- a_s / a_d per node ----------------
template <int C>
__global__ void k_asad(const float* __restrict__ h,
                       const float* __restrict__ asrc, const float* __restrict__ adst,
                       float* __restrict__ a_s, float* __restrict__ a_d) {
    int i = blockIdx.x, lane = threadIdx.x;
    float ps = 0.f, pd = 0.f;
    for (int c = lane; c < C; c += 64) {
        float v = h[(size_t)i * C + c];
        ps += v * asrc[c];
        pd += v * adst[c];
    }
    for (int o = 32; o > 0; o >>= 1) {
        ps += __shfl_xor(ps, o);
        pd += __shfl_xor(pd, o);
    }
    if (lane == 0) { a_s[i] = ps; a_d[i] = pd; }
}

// ---------------- per-node online-softmax aggregation ----------------
template <int C, bool RELU>
__global__ void k_agg(const float* __restrict__ h, const float* __restrict__ a_s,
                      const float* __restrict__ a_d, const float* __restrict__ ae,
                      const float* __restrict__ aesum, const int* __restrict__ cnt,
                      const int* __restrict__ offs, const int* __restrict__ csr_src,
                      const int* __restrict__ csr_eid,
                      const float* __restrict__ bias,
                      float* __restrict__ out) {
    constexpr int CPL = (C + 63) / 64;
    int i = blockIdx.x;
    int lane = threadIdx.x;
    float adl = a_d[i];
    int deg = cnt[i];
    float loop_ae = aesum[i] / (float)(deg > 1 ? deg : 1);
    float al = a_s[i] + adl + loop_ae;
    al = al > 0.f ? al : al * NEG_SLOPE;
    float m = al;          // self-loop initializes the online softmax
    float denom = 1.0f;    // exp(al - al)
    float acc[CPL];
#pragma unroll
    for (int j = 0; j < CPL; j++) {
        int c = lane + 64 * j;
        acc[j] = (c < C) ? h[(size_t)i * C + c] : 0.f;
    }
    int rs = offs[i], re = offs[i + 1];
    for (int base = rs; base < re; base += 64) {
        int el = base + lane;
        bool valid = el < re;
        float alpha = -3.4e38f;
        int s = 0;
        if (valid) {
            s = csr_src[el];
            int eid = csr_eid[el];
            float a = a_s[s] + adl + ae[eid];
            alpha = a > 0.f ? a : a * NEG_SLOPE;
        }
        float cmax = alpha;
        for (int o = 32; o > 0; o >>= 1) cmax = fmaxf(cmax, __shfl_xor(cmax, o));
        float nm = fmaxf(m, cmax);
        float scale = __expf(m - nm);
        denom *= scale;
#pragma unroll
        for (int j = 0; j < CPL; j++) acc[j] *= scale;
        m = nm;
        float ex = valid ? __expf(alpha - m) : 0.f;
        float esum = ex;
        for (int o = 32; o > 0; o >>= 1) esum += __shfl_xor(esum, o);
        denom += esum;
        int nvalid = (re - base) < 64 ? (re - base) : 64;
        for (int t = 0; t < nvalid; t++) {
            float ext = __shfl(ex, t);
            int st = __shfl(s, t);
            const float* hrow = h + (size_t)st * C;
#pragma unroll
            for (int j = 0; j < CPL; j++) {
                int c = lane + 64 * j;
                if (c < C) acc[j] += ext * hrow[c];
            }
        }
    }
    float inv = 1.0f / (denom + EPS_F);
#pragma unroll
    for (int j = 0; j < CPL; j++) {
        int c = lane + 64 * j;
        if (c < C) {
            float v = acc[j] * inv + bias[c];
            if (RELU) v = v > 0.f ? v : 0.f;
            out[(size_t)i * C + c] = v;
        }
    }
}

extern "C" void kernel_launch(void* const* d_in, const int* in_sizes, int n_in,
                              void* d_out, int out_size, void* d_ws, size_t ws_size,
                              hipStream_t stream) {
    const float* x    = (const float*)d_in[0];
    const int* ei     = (const int*)d_in[1];
    const float* ea   = (const float*)d_in[2];
    const float* W1   = (const float*)d_in[3];
    const float* as1v = (const float*)d_in[4];
    const float* ad1v = (const float*)d_in[5];
    const float* We1  = (const float*)d_in[6];
    const float* aev1 = (const float*)d_in[7];
    const float* b1   = (const float*)d_in[8];
    const float* W2   = (const float*)d_in[9];
    const float* as2v = (const float*)d_in[10];
    const float* ad2v = (const float*)d_in[11];
    const float* We2  = (const float*)d_in[12];
    const float* aev2 = (const float*)d_in[13];
    const float* b2   = (const float*)d_in[14];

    const int* src = ei;
    const int* dst = ei + N_EDGES;

    char* w = (char*)d_ws;
    size_t off = 0;
    auto alloc = [&](size_t bytes) -> void* {
        void* p = w + off;
        off += bytes;
        off = (off + 255) & ~(size_t)255;
        return p;
    };
    float* h1     = (float*)alloc((size_t)N_NODES * H_DIM * 4);
    float* h2     = (float*)alloc((size_t)N_NODES * O_DIM * 4);
    float* ae1    = (float*)alloc((size_t)N_EDGES * 4);
    float* ae2    = (float*)alloc((size_t)N_EDGES * 4);
    float* aesum1 = (float*)alloc((size_t)N_NODES * 4);
    float* aesum2 = (float*)alloc((size_t)N_NODES * 4);
    int* cnt      = (int*)alloc((size_t)N_NODES * 4);
    int* offs     = (int*)alloc((size_t)(N_NODES + 1) * 4);
    int* cursor   = (int*)alloc((size_t)N_NODES * 4);
    int* csr_src  = (int*)alloc((size_t)N_EDGES * 4);
    int* csr_eid  = (int*)alloc((size_t)N_EDGES * 4);
    int* bsum     = (int*)alloc(64 * 4);
    int* bpre     = (int*)alloc(64 * 4);
    float* wv1    = (float*)alloc(64 * 4);
    float* wv2    = (float*)alloc(64 * 4);
    float* a_s1   = (float*)alloc((size_t)N_NODES * 4);
    float* a_d1   = (float*)alloc((size_t)N_NODES * 4);
    float* a_s2   = (float*)alloc((size_t)N_NODES * 4);
    float* a_d2   = (float*)alloc((size_t)N_NODES * 4);

    hipMemsetAsync(cnt, 0, (size_t)N_NODES * 4, stream);
    hipMemsetAsync(aesum1, 0, (size_t)N_NODES * 4, stream);
    hipMemsetAsync(aesum2, 0, (size_t)N_NODES * 4, stream);

    k_wevec<<<1, 128, 0, stream>>>(We1, aev1, We2, aev2, wv1, wv2);
    k_edge_ae<<<(N_EDGES + 255) / 256, 256, 0, stream>>>(ea, dst, wv1, wv2,
                                                         ae1, ae2, aesum1, aesum2, cnt);
    int nb = (N_NODES + 1023) / 1024;
    k_scan1<<<nb, 256, 0, stream>>>(cnt, bsum, N_NODES);
    k_scan2<<<1, 64, 0, stream>>>(bsum, bpre, offs, nb, N_NODES);
    k_scan3<<<nb, 256, 0, stream>>>(cnt, bpre, offs, N_NODES);
    hipMemcpyAsync(cursor, offs, (size_t)N_NODES * 4, hipMemcpyDeviceToDevice, stream);
    k_scatter<<<(N_EDGES + 255) / 256, 256, 0, stream>>>(src, dst, cursor, csr_src, csr_eid);

    float* out = (float*)d_out;                       // [N, O]
    float* h_out = out + (size_t)N_NODES * O_DIM;     // [N, H] = relu(x1)

    // Layer 1: h1 = x @ W1   (50000x256 @ 256x128)
    {
        dim3 grid((N_NODES + 63) / 64, H_DIM / 64);
        k_gemm<64, 64, 16, 4, 4><<<grid, 256, 0, stream>>>(x, W1, h1, N_NODES, H_DIM, F_DIM);
    }
    k_asad<H_DIM><<<N_NODES, 64, 0, stream>>>(h1, as1v, ad1v, a_s1, a_d1);
    k_agg<H_DIM, true><<<N_NODES, 64, 0, stream>>>(h1, a_s1, a_d1, ae1, aesum1, cnt,
                                                   offs, csr_src, csr_eid, b1, h_out);

    // Layer 2: h2 = relu(x1) @ W2   (50000x128 @ 128x32)
    {
        dim3 grid((N_NODES + 63) / 64, O_DIM / 32);
        k_gemm<64, 32, 16, 4, 4><<<grid, 128, 0, stream>>>(h_out, W2, h2, N_NODES, O_DIM, H_DIM);
    }
    k_asad<O_DIM><<<N_NODES, 64, 0, stream>>>(h2, as2v, ad2v, a_s2, a_d2);
    k_agg<O_DIM, false><<<N_NODES, 64, 0, stream>>>(h2, a_s2, a_d2, ae2, aesum2, cnt,
                                                    offs, csr_src, csr_eid, b2, out);
}

// Round 3
// 473.338 us; speedup vs baseline: 1.2859x; 1.2859x over previous
//
#include <hip/hip_runtime.h>

#define N_NODES 50000
#define N_EDGES 500000
#define F_DIM 256
#define ED_DIM 64
#define H_DIM 128
#define O_DIM 32
#define NEG_SLOPE 0.2f
#define EPS_F 1e-16f

typedef __attribute__((ext_vector_type(8))) short short8;
typedef __attribute__((ext_vector_type(4))) float floatx4;

__device__ __forceinline__ unsigned short f2bf(float f) {
    union { float f; unsigned u; } c; c.f = f;
    unsigned u = c.u;
    return (unsigned short)((u + 0x7fffu + ((u >> 16) & 1u)) >> 16);
}

// ---------------- we_vec = We @ a_edge (both layers) ----------------
__global__ void k_wevec(const float* __restrict__ We1, const float* __restrict__ aev1,
                        const float* __restrict__ We2, const float* __restrict__ aev2,
                        float* __restrict__ wv1, float* __restrict__ wv2) {
    int t = threadIdx.x;
    if (t < 64) {
        float s = 0.f;
        for (int c = 0; c < H_DIM; c++) s += We1[t * H_DIM + c] * aev1[c];
        wv1[t] = s;
    } else {
        int k = t - 64;
        float s = 0.f;
        for (int c = 0; c < O_DIM; c++) s += We2[k * O_DIM + c] * aev2[c];
        wv2[k] = s;
    }
}

// ------------- transpose+convert W1, W2 to bf16 (one-time, tiny) -------------
__global__ void k_wconv(const float* __restrict__ W1, const float* __restrict__ W2,
                        unsigned short* __restrict__ W1T, unsigned short* __restrict__ W2T) {
    int gid = blockIdx.x * blockDim.x + threadIdx.x;
    int stride = gridDim.x * blockDim.x;
    for (int i = gid; i < H_DIM * F_DIM; i += stride) {   // W1T[n][k], n<128,k<256
        int n = i >> 8, k = i & 255;
        W1T[i] = f2bf(W1[k * H_DIM + n]);
    }
    for (int i = gid; i < O_DIM * H_DIM; i += stride) {   // W2T[n][k], n<32,k<128
        int n = i >> 7, k = i & 127;
        W2T[i] = f2bf(W2[k * O_DIM + n]);
    }
}

// ------------- per-edge a_e (both layers) + degree histogram -------------
__global__ void k_edge_ae(const float* __restrict__ ea, const int* __restrict__ dst,
                          const float* __restrict__ wv1, const float* __restrict__ wv2,
                          float* __restrict__ ae1, float* __restrict__ ae2,
                          float* __restrict__ aesum1, float* __restrict__ aesum2,
                          int* __restrict__ cnt) {
    int e = blockIdx.x * blockDim.x + threadIdx.x;
    if (e >= N_EDGES) return;
    const float4* row = (const float4*)(ea + (size_t)e * ED_DIM);
    float s1 = 0.f, s2 = 0.f;
#pragma unroll
    for (int j = 0; j < ED_DIM / 4; j++) {
        float4 q = row[j];
        int k = j * 4;
        s1 += q.x * wv1[k] + q.y * wv1[k + 1] + q.z * wv1[k + 2] + q.w * wv1[k + 3];
        s2 += q.x * wv2[k] + q.y * wv2[k + 1] + q.z * wv2[k + 2] + q.w * wv2[k + 3];
    }
    ae1[e] = s1; ae2[e] = s2;
    int d = dst[e];
    atomicAdd(&aesum1[d], s1);
    atomicAdd(&aesum2[d], s2);
    atomicAdd(&cnt[d], 1);
}

// ---------------- prefix-sum (CSR offsets), 3 kernels ----------------
__global__ void k_scan1(const int* __restrict__ cnt, int* __restrict__ bsum, int n) {
    __shared__ int sh[256];
    int b = blockIdx.x, t = threadIdx.x;
    int base = b * 1024;
    int s = 0;
    for (int j = 0; j < 4; j++) {
        int idx = base + t * 4 + j;
        if (idx < n) s += cnt[idx];
    }
    sh[t] = s; __syncthreads();
    for (int o = 128; o > 0; o >>= 1) {
        if (t < o) sh[t] += sh[t + o];
        __syncthreads();
    }
    if (t == 0) bsum[b] = sh[0];
}

__global__ void k_scan2(const int* __restrict__ bsum, int* __restrict__ bpre,
                        int* __restrict__ offs, int nb, int n) {
    if (threadIdx.x == 0) {
        int run = 0;
        for (int b = 0; b < nb; b++) { bpre[b] = run; run += bsum[b]; }
        offs[n] = run;
    }
}

__global__ void k_scan3(const int* __restrict__ cnt, const int* __restrict__ bpre,
                        int* __restrict__ offs, int n) {
    __shared__ int sh[256];
    int b = blockIdx.x, t = threadIdx.x;
    int base = b * 1024;
    int v[4]; int s = 0;
    for (int j = 0; j < 4; j++) {
        int idx = base + t * 4 + j;
        v[j] = (idx < n) ? cnt[idx] : 0;
        s += v[j];
    }
    sh[t] = s; __syncthreads();
    for (int o = 1; o < 256; o <<= 1) {
        int x = (t >= o) ? sh[t - o] : 0;
        __syncthreads();
        sh[t] += x;
        __syncthreads();
    }
    int texcl = sh[t] - s + bpre[b];
    int run = 0;
    for (int j = 0; j < 4; j++) {
        int idx = base + t * 4 + j;
        if (idx < n) offs[idx] = texcl + run;
        run += v[j];
    }
}

__global__ void k_scatter(const int* __restrict__ src, const int* __restrict__ dst,
                          int* __restrict__ cursor,
                          int* __restrict__ csr_src, int* __restrict__ csr_eid) {
    int e = blockIdx.x * blockDim.x + threadIdx.x;
    if (e >= N_EDGES) return;
    int d = dst[e];
    int p = atomicAdd(&cursor[d], 1);
    csr_src[p] = src[e];
    csr_eid[p] = e;
}

// =============== MFMA GEMM layer 1: h1 = x@W1, fused a_s/a_d ===============
// A: [M,256] fp32, BT: W1T bf16 [128][256]. Out: C [M,128] fp32, a_s, a_d.
// Block: 256 thr / 4 waves. BM=128, BN=128, BK=32. LDS rows padded to 40 shorts.
__global__ __launch_bounds__(256) void k_gemm1(const float* __restrict__ A,
        const unsigned short* __restrict__ BT,
        const float* __restrict__ asv, const float* __restrict__ adv,
        float* __restrict__ C, float* __restrict__ a_s, float* __restrict__ a_d, int M) {
    __shared__ unsigned short As[128 * 40];
    __shared__ unsigned short Bs[128 * 40];
    int tid = threadIdx.x;
    int wave = tid >> 6, lane = tid & 63;
    int q = lane >> 4, r = lane & 15;
    int bm0 = blockIdx.x * 128;
    floatx4 acc[2][8];
#pragma unroll
    for (int a = 0; a < 2; a++)
#pragma unroll
        for (int b = 0; b < 8; b++) acc[a][b] = (floatx4){0.f, 0.f, 0.f, 0.f};

    int rr = tid >> 3;        // 0..31
    int kc = tid & 7;         // k-chunk (4 floats)
    for (int k0 = 0; k0 < 256; k0 += 32) {
        // stage A (fp32 -> bf16)
#pragma unroll
        for (int i = 0; i < 4; i++) {
            int row = rr + 32 * i;
            int gr = bm0 + row;
            float4 v = make_float4(0.f, 0.f, 0.f, 0.f);
            if (gr < M) v = *(const float4*)(A + (size_t)gr * 256 + k0 + kc * 4);
            unsigned lo = (unsigned)f2bf(v.x) | ((unsigned)f2bf(v.y) << 16);
            unsigned hi = (unsigned)f2bf(v.z) | ((unsigned)f2bf(v.w) << 16);
            *(uint2*)&As[row * 40 + kc * 4] = make_uint2(lo, hi);
        }
        // stage B (already bf16, transposed): 128 n x 32 k
#pragma unroll
        for (int i = 0; i < 2; i++) {
            int idx = tid + 256 * i;            // 0..511
            int n = idx >> 2, ck = idx & 3;
            *(uint4*)&Bs[n * 40 + ck * 8] = *(const uint4*)(BT + n * 256 + k0 + ck * 8);
        }
        __syncthreads();
        short8 af[2], bf[8];
#pragma unroll
        for (int rt = 0; rt < 2; rt++)
            af[rt] = *(const short8*)&As[(wave * 32 + rt * 16 + r) * 40 + q * 8];
#pragma unroll
        for (int nt = 0; nt < 8; nt++)
            bf[nt] = *(const short8*)&Bs[(nt * 16 + r) * 40 + q * 8];
#pragma unroll
        for (int rt = 0; rt < 2; rt++)
#pragma unroll
            for (int nt = 0; nt < 8; nt++)
                acc[rt][nt] = __builtin_amdgcn_mfma_f32_16x16x32_bf16(af[rt], bf[nt], acc[rt][nt], 0, 0, 0);
        __syncthreads();
    }
    // epilogue: store C rows + fused a_s/a_d
#pragma unroll
    for (int rt = 0; rt < 2; rt++) {
        int rowb = bm0 + wave * 32 + rt * 16 + q * 4;
        float ps[4] = {0.f, 0.f, 0.f, 0.f}, pd[4] = {0.f, 0.f, 0.f, 0.f};
#pragma unroll
        for (int nt = 0; nt < 8; nt++) {
            int col = nt * 16 + r;
            float av = asv[col], dv = adv[col];
#pragma unroll
            for (int reg = 0; reg < 4; reg++) {
                float v = acc[rt][nt][reg];
                if (rowb + reg < M) C[(size_t)(rowb + reg) * 128 + col] = v;
                ps[reg] += v * av;
                pd[reg] += v * dv;
            }
        }
#pragma unroll
        for (int reg = 0; reg < 4; reg++) {
#pragma unroll
            for (int off = 1; off < 16; off <<= 1) {
                ps[reg] += __shfl_xor(ps[reg], off);
                pd[reg] += __shfl_xor(pd[reg], off);
            }
        }
        if (r == 0) {
#pragma unroll
            for (int reg = 0; reg < 4; reg++) {
                if (rowb + reg < M) { a_s[rowb + reg] = ps[reg]; a_d[rowb + reg] = pd[reg]; }
            }
        }
    }
}

// =============== MFMA GEMM layer 2: h2 = relu(x1)@W2, fused a_s/a_d ===============
// A: [M,128] fp32, BT: W2T bf16 [32][128]. Out: C [M,32] fp32, a_s, a_d.
__global__ __launch_bounds__(256) void k_gemm2(const float* __restrict__ A,
        const unsigned short* __restrict__ BT,
        const float* __restrict__ asv, const float* __restrict__ adv,
        float* __restrict__ C, float* __restrict__ a_s, float* __restrict__ a_d, int M) {
    __shared__ unsigned short As[128 * 40];
    __shared__ unsigned short Bs[32 * 40];
    int tid = threadIdx.x;
    int wave = tid >> 6, lane = tid & 63;
    int q = lane >> 4, r = lane & 15;
    int bm0 = blockIdx.x * 128;
    floatx4 acc[2][2];
#pragma unroll
    for (int a = 0; a < 2; a++)
#pragma unroll
        for (int b = 0; b < 2; b++) acc[a][b] = (floatx4){0.f, 0.f, 0.f, 0.f};

    int rr = tid >> 3;
    int kc = tid & 7;
    for (int k0 = 0; k0 < 128; k0 += 32) {
#pragma unroll
        for (int i = 0; i < 4; i++) {
            int row = rr + 32 * i;
            int gr = bm0 + row;
            float4 v = make_float4(0.f, 0.f, 0.f, 0.f);
            if (gr < M) v = *(const float4*)(A + (size_t)gr * 128 + k0 + kc * 4);
            unsigned lo = (unsigned)f2bf(v.x) | ((unsigned)f2bf(v.y) << 16);
            unsigned hi = (unsigned)f2bf(v.z) | ((unsigned)f2bf(v.w) << 16);
            *(uint2*)&As[row * 40 + kc * 4] = make_uint2(lo, hi);
        }
        if (tid < 128) {
            int n = tid >> 2, ck = tid & 3;
            *(uint4*)&Bs[n * 40 + ck * 8] = *(const uint4*)(BT + n * 128 + k0 + ck * 8);
        }
        __syncthreads();
        short8 af[2], bf[2];
#pragma unroll
        for (int rt = 0; rt < 2; rt++)
            af[rt] = *(const short8*)&As[(wave * 32 + rt * 16 + r) * 40 + q * 8];
#pragma unroll
        for (int nt = 0; nt < 2; nt++)
            bf[nt] = *(const short8*)&Bs[(nt * 16 + r) * 40 + q * 8];
#pragma unroll
        for (int rt = 0; rt < 2; rt++)
#pragma unroll
            for (int nt = 0; nt < 2; nt++)
                acc[rt][nt] = __builtin_amdgcn_mfma_f32_16x16x32_bf16(af[rt], bf[nt], acc[rt][nt], 0, 0, 0);
        __syncthreads();
    }
#pragma unroll
    for (int rt = 0; rt < 2; rt++) {
        int rowb = bm0 + wave * 32 + rt * 16 + q * 4;
        float ps[4] = {0.f, 0.f, 0.f, 0.f}, pd[4] = {0.f, 0.f, 0.f, 0.f};
#pragma unroll
        for (int nt = 0; nt < 2; nt++) {
            int col = nt * 16 + r;
            float av = asv[col], dv = adv[col];
#pragma unroll
            for (int reg = 0; reg < 4; reg++) {
                float v = acc[rt][nt][reg];
                if (rowb + reg < M) C[(size_t)(rowb + reg) * 32 + col] = v;
                ps[reg] += v * av;
                pd[reg] += v * dv;
            }
        }
#pragma unroll
        for (int reg = 0; reg < 4; reg++) {
#pragma unroll
            for (int off = 1; off < 16; off <<= 1) {
                ps[reg] += __shfl_xor(ps[reg], off);
                pd[reg] += __shfl_xor(pd[reg], off);
            }
        }
        if (r == 0) {
#pragma unroll
            for (int reg = 0; reg < 4; reg++) {
                if (rowb + reg < M) { a_s[rowb + reg] = ps[reg]; a_d[rowb + reg] = pd[reg]; }
            }
        }
    }
}

// ---------------- per-node online-softmax aggregation, C=128 (float2/lane) ----------------
__global__ void k_agg128(const float* __restrict__ h, const float* __restrict__ a_s,
                         const float* __restrict__ a_d, const float* __restrict__ ae,
                         const float* __restrict__ aesum, const int* __restrict__ cnt,
                         const int* __restrict__ offs, const int* __restrict__ csr_src,
                         const int* __restrict__ csr_eid,
                         const float* __restrict__ bias,
                         float* __restrict__ out) {
    int i = blockIdx.x;
    int lane = threadIdx.x;
    float adl = a_d[i];
    int deg = cnt[i];
    float loop_ae = aesum[i] / (float)(deg > 1 ? deg : 1);
    float al = a_s[i] + adl + loop_ae;
    al = al > 0.f ? al : al * NEG_SLOPE;
    float m = al;
    float denom = 1.0f;
    float2 acc = *(const float2*)(h + (size_t)i * 128 + 2 * lane);  // self-loop term
    int rs = offs[i], re = offs[i + 1];
    for (int base = rs; base < re; base += 64) {
        int el = base + lane;
        bool valid = el < re;
        float alpha = -3.4e38f;
        int s = 0;
        if (valid) {
            s = csr_src[el];
            int eid = csr_eid[el];
            float a = a_s[s] + adl + ae[eid];
            alpha = a > 0.f ? a : a * NEG_SLOPE;
        }
        float cmax = alpha;
        for (int o = 32; o > 0; o >>= 1) cmax = fmaxf(cmax, __shfl_xor(cmax, o));
        float nm = fmaxf(m, cmax);
        float scale = __expf(m - nm);
        denom *= scale;
        acc.x *= scale; acc.y *= scale;
        m = nm;
        float ex = valid ? __expf(alpha - m) : 0.f;
        float esum = ex;
        for (int o = 32; o > 0; o >>= 1) esum += __shfl_xor(esum, o);
        denom += esum;
        int nvalid = (re - base) < 64 ? (re - base) : 64;
        for (int t = 0; t < nvalid; t++) {
            float ext = __shfl(ex, t);
            int st = __shfl(s, t);
            float2 hv = ((const float2*)(h + (size_t)st * 128))[lane];
            acc.x += ext * hv.x;
            acc.y += ext * hv.y;
        }
    }
    float inv = 1.0f / (denom + EPS_F);
    float2 bv = ((const float2*)bias)[lane];
    float ox = acc.x * inv + bv.x;
    float oy = acc.y * inv + bv.y;
    ox = ox > 0.f ? ox : 0.f;   // relu (layer 1 output feeds relu)
    oy = oy > 0.f ? oy : 0.f;
    ((float2*)(out + (size_t)i * 128))[lane] = make_float2(ox, oy);
}

// ---------------- per-node online-softmax aggregation, C=32 ----------------
__global__ void k_agg32(const float* __restrict__ h, const float* __restrict__ a_s,
                        const float* __restrict__ a_d, const float* __restrict__ ae,
                        const float* __restrict__ aesum, const int* __restrict__ cnt,
                        const int* __restrict__ offs, const int* __restrict__ csr_src,
                        const int* __restrict__ csr_eid,
                        const float* __restrict__ bias,
                        float* __restrict__ out) {
    int i = blockIdx.x;
    int lane = threadIdx.x;
    float adl = a_d[i];
    int deg = cnt[i];
    float loop_ae = aesum[i] / (float)(deg > 1 ? deg : 1);
    float al = a_s[i] + adl + loop_ae;
    al = al > 0.f ? al : al * NEG_SLOPE;
    float m = al;
    float denom = 1.0f;
    float acc = (lane < 32) ? h[(size_t)i * 32 + lane] : 0.f;
    int rs = offs[i], re = offs[i + 1];
    for (int base = rs; base < re; base += 64) {
        int el = base + lane;
        bool valid = el < re;
        float alpha = -3.4e38f;
        int s = 0;
        if (valid) {
            s = csr_src[el];
            int eid = csr_eid[el];
            float a = a_s[s] + adl + ae[eid];
            alpha = a > 0.f ? a : a * NEG_SLOPE;
        }
        float cmax = alpha;
        for (int o = 32; o > 0; o >>= 1) cmax = fmaxf(cmax, __shfl_xor(cmax, o));
        float nm = fmaxf(m, cmax);
        float scale = __expf(m - nm);
        denom *= scale;
        acc *= scale;
        m = nm;
        float ex = valid ? __expf(alpha - m) : 0.f;
        float esum = ex;
        for (int o = 32; o > 0; o >>= 1) esum += __shfl_xor(esum, o);
        denom += esum;
        int nvalid = (re - base) < 64 ? (re - base) : 64;
        for (int t = 0; t < nvalid; t++) {
            float ext = __shfl(ex, t);
            int st = __shfl(s, t);
            if (lane < 32) acc += ext * h[(size_t)st * 32 + lane];
        }
    }
    if (lane < 32) {
        float inv = 1.0f / (denom + EPS_F);
        out[(size_t)i * 32 + lane] = acc * inv + bias[lane];
    }
}

extern "C" void kernel_launch(void* const* d_in, const int* in_sizes, int n_in,
                              void* d_out, int out_size, void* d_ws, size_t ws_size,
                              hipStream_t stream) {
    const float* x    = (const float*)d_in[0];
    const int* ei     = (const int*)d_in[1];
    const float* ea   = (const float*)d_in[2];
    const float* W1   = (const float*)d_in[3];
    const float* as1v = (const float*)d_in[4];
    const float* ad1v = (const float*)d_in[5];
    const float* We1  = (const float*)d_in[6];
    const float* aev1 = (const float*)d_in[7];
    const float* b1   = (const float*)d_in[8];
    const float* W2   = (const float*)d_in[9];
    const float* as2v = (const float*)d_in[10];
    const float* ad2v = (const float*)d_in[11];
    const float* We2  = (const float*)d_in[12];
    const float* aev2 = (const float*)d_in[13];
    const float* b2   = (const float*)d_in[14];

    const int* src = ei;
    const int* dst = ei + N_EDGES;

    char* w = (char*)d_ws;
    size_t off = 0;
    auto alloc = [&](size_t bytes) -> void* {
        void* p = w + off;
        off += bytes;
        off = (off + 255) & ~(size_t)255;
        return p;
    };
    float* h1     = (float*)alloc((size_t)N_NODES * H_DIM * 4);
    float* h2     = (float*)alloc((size_t)N_NODES * O_DIM * 4);
    float* ae1    = (float*)alloc((size_t)N_EDGES * 4);
    float* ae2    = (float*)alloc((size_t)N_EDGES * 4);
    float* aesum1 = (float*)alloc((size_t)N_NODES * 4);
    float* aesum2 = (float*)alloc((size_t)N_NODES * 4);
    int* cnt      = (int*)alloc((size_t)N_NODES * 4);
    int* offs     = (int*)alloc((size_t)(N_NODES + 1) * 4);
    int* cursor   = (int*)alloc((size_t)N_NODES * 4);
    int* csr_src  = (int*)alloc((size_t)N_EDGES * 4);
    int* csr_eid  = (int*)alloc((size_t)N_EDGES * 4);
    int* bsum     = (int*)alloc(64 * 4);
    int* bpre     = (int*)alloc(64 * 4);
    float* wv1    = (float*)alloc(64 * 4);
    float* wv2    = (float*)alloc(64 * 4);
    float* a_s1   = (float*)alloc((size_t)N_NODES * 4);
    float* a_d1   = (float*)alloc((size_t)N_NODES * 4);
    float* a_s2   = (float*)alloc((size_t)N_NODES * 4);
    float* a_d2   = (float*)alloc((size_t)N_NODES * 4);
    unsigned short* W1T = (unsigned short*)alloc((size_t)H_DIM * F_DIM * 2);
    unsigned short* W2T = (unsigned short*)alloc((size_t)O_DIM * H_DIM * 2);

    hipMemsetAsync(cnt, 0, (size_t)N_NODES * 4, stream);
    hipMemsetAsync(aesum1, 0, (size_t)N_NODES * 4, stream);
    hipMemsetAsync(aesum2, 0, (size_t)N_NODES * 4, stream);

    k_wevec<<<1, 128, 0, stream>>>(We1, aev1, We2, aev2, wv1, wv2);
    k_wconv<<<32, 256, 0, stream>>>(W1, W2, W1T, W2T);
    k_edge_ae<<<(N_EDGES + 255) / 256, 256, 0, stream>>>(ea, dst, wv1, wv2,
                                                         ae1, ae2, aesum1, aesum2, cnt);
    int nb = (N_NODES + 1023) / 1024;
    k_scan1<<<nb, 256, 0, stream>>>(cnt, bsum, N_NODES);
    k_scan2<<<1, 64, 0, stream>>>(bsum, bpre, offs, nb, N_NODES);
    k_scan3<<<nb, 256, 0, stream>>>(cnt, bpre, offs, N_NODES);
    hipMemcpyAsync(cursor, offs, (size_t)N_NODES * 4, hipMemcpyDeviceToDevice, stream);
    k_scatter<<<(N_EDGES + 255) / 256, 256, 0, stream>>>(src, dst, cursor, csr_src, csr_eid);

    float* out = (float*)d_out;                       // [N, O]
    float* h_out = out + (size_t)N_NODES * O_DIM;     // [N, H] = relu(x1)

    // Layer 1: h1 = x @ W1 (MFMA bf16) + fused a_s1/a_d1
    k_gemm1<<<(N_NODES + 127) / 128, 256, 0, stream>>>(x, W1T, as1v, ad1v,
                                                       h1, a_s1, a_d1, N_NODES);
    k_agg128<<<N_NODES, 64, 0, stream>>>(h1, a_s1, a_d1, ae1, aesum1, cnt,
                                         offs, csr_src, csr_eid, b1, h_out);

    // Layer 2: h2 = relu(x1) @ W2 (MFMA bf16) + fused a_s2/a_d2
    k_gemm2<<<(N_NODES + 127) / 128, 256, 0, stream>>>(h_out, W2T, as2v, ad2v,
                                                       h2, a_s2, a_d2, N_NODES);
    k_agg32<<<N_NODES, 64, 0, stream>>>(h2, a_s2, a_d2, ae2, aesum2, cnt,
                                        offs, csr_src, csr_eid, b2, out);
}

// Round 4
// 465.768 us; speedup vs baseline: 1.3068x; 1.0163x over previous
//
#include <hip/hip_runtime.h>

#define N_NODES 50000
#define N_EDGES 500000
#define F_DIM 256
#define ED_DIM 64
#define H_DIM 128
#define O_DIM 32
#define NEG_SLOPE 0.2f
#define EPS_F 1e-16f

typedef __attribute__((ext_vector_type(8))) short short8;
typedef __attribute__((ext_vector_type(4))) float floatx4;

__device__ __forceinline__ unsigned short f2bf(float f) {
    union { float f; unsigned u; } c; c.f = f;
    unsigned u = c.u;
    return (unsigned short)((u + 0x7fffu + ((u >> 16) & 1u)) >> 16);
}

// ---------------- we_vec = We @ a_edge (both layers) ----------------
__global__ void k_wevec(const float* __restrict__ We1, const float* __restrict__ aev1,
                        const float* __restrict__ We2, const float* __restrict__ aev2,
                        float* __restrict__ wv1, float* __restrict__ wv2) {
    int t = threadIdx.x;
    if (t < 64) {
        float s = 0.f;
        for (int c = 0; c < H_DIM; c++) s += We1[t * H_DIM + c] * aev1[c];
        wv1[t] = s;
    } else {
        int k = t - 64;
        float s = 0.f;
        for (int c = 0; c < O_DIM; c++) s += We2[k * O_DIM + c] * aev2[c];
        wv2[k] = s;
    }
}

// ------------- transpose+convert W1, W2 to bf16 (one-time, tiny) -------------
__global__ void k_wconv(const float* __restrict__ W1, const float* __restrict__ W2,
                        unsigned short* __restrict__ W1T, unsigned short* __restrict__ W2T) {
    int gid = blockIdx.x * blockDim.x + threadIdx.x;
    int stride = gridDim.x * blockDim.x;
    for (int i = gid; i < H_DIM * F_DIM; i += stride) {   // W1T[n][k]
        int n = i >> 8, k = i & 255;
        W1T[i] = f2bf(W1[k * H_DIM + n]);
    }
    for (int i = gid; i < O_DIM * H_DIM; i += stride) {   // W2T[n][k]
        int n = i >> 7, k = i & 127;
        W2T[i] = f2bf(W2[k * O_DIM + n]);
    }
}

// ------------- per-edge a_e, coalesced: 16 lanes per edge row -------------
__global__ __launch_bounds__(256) void k_edge_ae(const float* __restrict__ ea,
                          const int* __restrict__ dst,
                          const float* __restrict__ wv1, const float* __restrict__ wv2,
                          float* __restrict__ ae1, float* __restrict__ ae2,
                          float* __restrict__ aesum1, float* __restrict__ aesum2,
                          int* __restrict__ cnt) {
    int tid = threadIdx.x;
    int wave = tid >> 6, lane = tid & 63;
    int sub = lane & 15;     // which float4 of the 64-float row
    int eo = lane >> 4;      // which of 4 edges this wave handles per iter
    float4 w1 = ((const float4*)wv1)[sub];
    float4 w2 = ((const float4*)wv2)[sub];
    int e0 = (blockIdx.x * 4 + wave) * 4 + eo;
    int stride = gridDim.x * 16;
    for (int e = e0; e < N_EDGES; e += stride) {
        float4 q = *(const float4*)(ea + (size_t)e * ED_DIM + sub * 4);
        float s1 = q.x * w1.x + q.y * w1.y + q.z * w1.z + q.w * w1.w;
        float s2 = q.x * w2.x + q.y * w2.y + q.z * w2.z + q.w * w2.w;
#pragma unroll
        for (int o = 1; o < 16; o <<= 1) {
            s1 += __shfl_xor(s1, o);
            s2 += __shfl_xor(s2, o);
        }
        if (sub == 0) {
            ae1[e] = s1; ae2[e] = s2;
            int d = dst[e];
            atomicAdd(&aesum1[d], s1);
            atomicAdd(&aesum2[d], s2);
            atomicAdd(&cnt[d], 1);
        }
    }
}

// ---------------- prefix-sum (CSR offsets), 3 kernels ----------------
__global__ void k_scan1(const int* __restrict__ cnt, int* __restrict__ bsum, int n) {
    __shared__ int sh[256];
    int b = blockIdx.x, t = threadIdx.x;
    int base = b * 1024;
    int s = 0;
    for (int j = 0; j < 4; j++) {
        int idx = base + t * 4 + j;
        if (idx < n) s += cnt[idx];
    }
    sh[t] = s; __syncthreads();
    for (int o = 128; o > 0; o >>= 1) {
        if (t < o) sh[t] += sh[t + o];
        __syncthreads();
    }
    if (t == 0) bsum[b] = sh[0];
}

__global__ void k_scan2(const int* __restrict__ bsum, int* __restrict__ bpre,
                        int* __restrict__ offs, int nb, int n) {
    if (threadIdx.x == 0) {
        int run = 0;
        for (int b = 0; b < nb; b++) { bpre[b] = run; run += bsum[b]; }
        offs[n] = run;
    }
}

__global__ void k_scan3(const int* __restrict__ cnt, const int* __restrict__ bpre,
                        int* __restrict__ offs, int n) {
    __shared__ int sh[256];
    int b = blockIdx.x, t = threadIdx.x;
    int base = b * 1024;
    int v[4]; int s = 0;
    for (int j = 0; j < 4; j++) {
        int idx = base + t * 4 + j;
        v[j] = (idx < n) ? cnt[idx] : 0;
        s += v[j];
    }
    sh[t] = s; __syncthreads();
    for (int o = 1; o < 256; o <<= 1) {
        int x = (t >= o) ? sh[t - o] : 0;
        __syncthreads();
        sh[t] += x;
        __syncthreads();
    }
    int texcl = sh[t] - s + bpre[b];
    int run = 0;
    for (int j = 0; j < 4; j++) {
        int idx = base + t * 4 + j;
        if (idx < n) offs[idx] = texcl + run;
        run += v[j];
    }
}

__global__ void k_scatter(const int* __restrict__ src, const int* __restrict__ dst,
                          int* __restrict__ cursor,
                          int* __restrict__ csr_src, int* __restrict__ csr_eid) {
    int e = blockIdx.x * blockDim.x + threadIdx.x;
    if (e >= N_EDGES) return;
    int d = dst[e];
    int p = atomicAdd(&cursor[d], 1);
    csr_src[p] = src[e];
    csr_eid[p] = e;
}

// =============== MFMA GEMM layer 1: h1 = x@W1, fused a_s/a_d ===============
__global__ __launch_bounds__(256) void k_gemm1(const float* __restrict__ A,
        const unsigned short* __restrict__ BT,
        const float* __restrict__ asv, const float* __restrict__ adv,
        float* __restrict__ C, float* __restrict__ a_s, float* __restrict__ a_d, int M) {
    __shared__ unsigned short As[128 * 40];
    __shared__ unsigned short Bs[128 * 40];
    int tid = threadIdx.x;
    int wave = tid >> 6, lane = tid & 63;
    int q = lane >> 4, r = lane & 15;
    int bm0 = blockIdx.x * 128;
    floatx4 acc[2][8];
#pragma unroll
    for (int a = 0; a < 2; a++)
#pragma unroll
        for (int b = 0; b < 8; b++) acc[a][b] = (floatx4){0.f, 0.f, 0.f, 0.f};

    int rr = tid >> 3;
    int kc = tid & 7;
    for (int k0 = 0; k0 < 256; k0 += 32) {
#pragma unroll
        for (int i = 0; i < 4; i++) {
            int row = rr + 32 * i;
            int gr = bm0 + row;
            float4 v = make_float4(0.f, 0.f, 0.f, 0.f);
            if (gr < M) v = *(const float4*)(A + (size_t)gr * 256 + k0 + kc * 4);
            unsigned lo = (unsigned)f2bf(v.x) | ((unsigned)f2bf(v.y) << 16);
            unsigned hi = (unsigned)f2bf(v.z) | ((unsigned)f2bf(v.w) << 16);
            *(uint2*)&As[row * 40 + kc * 4] = make_uint2(lo, hi);
        }
#pragma unroll
        for (int i = 0; i < 2; i++) {
            int idx = tid + 256 * i;
            int n = idx >> 2, ck = idx & 3;
            *(uint4*)&Bs[n * 40 + ck * 8] = *(const uint4*)(BT + n * 256 + k0 + ck * 8);
        }
        __syncthreads();
        short8 af[2], bf[8];
#pragma unroll
        for (int rt = 0; rt < 2; rt++)
            af[rt] = *(const short8*)&As[(wave * 32 + rt * 16 + r) * 40 + q * 8];
#pragma unroll
        for (int nt = 0; nt < 8; nt++)
            bf[nt] = *(const short8*)&Bs[(nt * 16 + r) * 40 + q * 8];
#pragma unroll
        for (int rt = 0; rt < 2; rt++)
#pragma unroll
            for (int nt = 0; nt < 8; nt++)
                acc[rt][nt] = __builtin_amdgcn_mfma_f32_16x16x32_bf16(af[rt], bf[nt], acc[rt][nt], 0, 0, 0);
        __syncthreads();
    }
#pragma unroll
    for (int rt = 0; rt < 2; rt++) {
        int rowb = bm0 + wave * 32 + rt * 16 + q * 4;
        float ps[4] = {0.f, 0.f, 0.f, 0.f}, pd[4] = {0.f, 0.f, 0.f, 0.f};
#pragma unroll
        for (int nt = 0; nt < 8; nt++) {
            int col = nt * 16 + r;
            float av = asv[col], dv = adv[col];
#pragma unroll
            for (int reg = 0; reg < 4; reg++) {
                float v = acc[rt][nt][reg];
                if (rowb + reg < M) C[(size_t)(rowb + reg) * 128 + col] = v;
                ps[reg] += v * av;
                pd[reg] += v * dv;
            }
        }
#pragma unroll
        for (int reg = 0; reg < 4; reg++) {
#pragma unroll
            for (int off = 1; off < 16; off <<= 1) {
                ps[reg] += __shfl_xor(ps[reg], off);
                pd[reg] += __shfl_xor(pd[reg], off);
            }
        }
        if (r == 0) {
#pragma unroll
            for (int reg = 0; reg < 4; reg++) {
                if (rowb + reg < M) { a_s[rowb + reg] = ps[reg]; a_d[rowb + reg] = pd[reg]; }
            }
        }
    }
}

// =============== MFMA GEMM layer 2: h2 = relu(x1)@W2, fused a_s/a_d ===============
__global__ __launch_bounds__(256) void k_gemm2(const float* __restrict__ A,
        const unsigned short* __restrict__ BT,
        const float* __restrict__ asv, const float* __restrict__ adv,
        float* __restrict__ C, float* __restrict__ a_s, float* __restrict__ a_d, int M) {
    __shared__ unsigned short As[128 * 40];
    __shared__ unsigned short Bs[32 * 40];
    int tid = threadIdx.x;
    int wave = tid >> 6, lane = tid & 63;
    int q = lane >> 4, r = lane & 15;
    int bm0 = blockIdx.x * 128;
    floatx4 acc[2][2];
#pragma unroll
    for (int a = 0; a < 2; a++)
#pragma unroll
        for (int b = 0; b < 2; b++) acc[a][b] = (floatx4){0.f, 0.f, 0.f, 0.f};

    int rr = tid >> 3;
    int kc = tid & 7;
    for (int k0 = 0; k0 < 128; k0 += 32) {
#pragma unroll
        for (int i = 0; i < 4; i++) {
            int row = rr + 32 * i;
            int gr = bm0 + row;
            float4 v = make_float4(0.f, 0.f, 0.f, 0.f);
            if (gr < M) v = *(const float4*)(A + (size_t)gr * 128 + k0 + kc * 4);
            unsigned lo = (unsigned)f2bf(v.x) | ((unsigned)f2bf(v.y) << 16);
            unsigned hi = (unsigned)f2bf(v.z) | ((unsigned)f2bf(v.w) << 16);
            *(uint2*)&As[row * 40 + kc * 4] = make_uint2(lo, hi);
        }
        if (tid < 128) {
            int n = tid >> 2, ck = tid & 3;
            *(uint4*)&Bs[n * 40 + ck * 8] = *(const uint4*)(BT + n * 128 + k0 + ck * 8);
        }
        __syncthreads();
        short8 af[2], bf[2];
#pragma unroll
        for (int rt = 0; rt < 2; rt++)
            af[rt] = *(const short8*)&As[(wave * 32 + rt * 16 + r) * 40 + q * 8];
#pragma unroll
        for (int nt = 0; nt < 2; nt++)
            bf[nt] = *(const short8*)&Bs[(nt * 16 + r) * 40 + q * 8];
#pragma unroll
        for (int rt = 0; rt < 2; rt++)
#pragma unroll
            for (int nt = 0; nt < 2; nt++)
                acc[rt][nt] = __builtin_amdgcn_mfma_f32_16x16x32_bf16(af[rt], bf[nt], acc[rt][nt], 0, 0, 0);
        __syncthreads();
    }
#pragma unroll
    for (int rt = 0; rt < 2; rt++) {
        int rowb = bm0 + wave * 32 + rt * 16 + q * 4;
        float ps[4] = {0.f, 0.f, 0.f, 0.f}, pd[4] = {0.f, 0.f, 0.f, 0.f};
#pragma unroll
        for (int nt = 0; nt < 2; nt++) {
            int col = nt * 16 + r;
            float av = asv[col], dv = adv[col];
#pragma unroll
            for (int reg = 0; reg < 4; reg++) {
                float v = acc[rt][nt][reg];
                if (rowb + reg < M) C[(size_t)(rowb + reg) * 32 + col] = v;
                ps[reg] += v * av;
                pd[reg] += v * dv;
            }
        }
#pragma unroll
        for (int reg = 0; reg < 4; reg++) {
#pragma unroll
            for (int off = 1; off < 16; off <<= 1) {
                ps[reg] += __shfl_xor(ps[reg], off);
                pd[reg] += __shfl_xor(pd[reg], off);
            }
        }
        if (r == 0) {
#pragma unroll
            for (int reg = 0; reg < 4; reg++) {
                if (rowb + reg < M) { a_s[rowb + reg] = ps[reg]; a_d[rowb + reg] = pd[reg]; }
            }
        }
    }
}

// ---------------- per-node online-softmax aggregation, C=128 ----------------
__global__ void k_agg128(const float* __restrict__ h, const float* __restrict__ a_s,
                         const float* __restrict__ a_d, const float* __restrict__ ae,
                         const float* __restrict__ aesum, const int* __restrict__ cnt,
                         const int* __restrict__ offs, const int* __restrict__ csr_src,
                         const int* __restrict__ csr_eid,
                         const float* __restrict__ bias,
                         float* __restrict__ out) {
    int i = blockIdx.x;
    int lane = threadIdx.x;
    float adl = a_d[i];
    int deg = cnt[i];
    float loop_ae = aesum[i] / (float)(deg > 1 ? deg : 1);
    float al = a_s[i] + adl + loop_ae;
    al = al > 0.f ? al : al * NEG_SLOPE;
    float m = al;
    float denom = 1.0f;
    float2 acc = *(const float2*)(h + (size_t)i * 128 + 2 * lane);
    int rs = offs[i], re = offs[i + 1];
    for (int base = rs; base < re; base += 64) {
        int el = base + lane;
        bool valid = el < re;
        float alpha = -3.4e38f;
        int s = 0;
        if (valid) {
            s = csr_src[el];
            int eid = csr_eid[el];
            float a = a_s[s] + adl + ae[eid];
            alpha = a > 0.f ? a : a * NEG_SLOPE;
        }
        float cmax = alpha;
        for (int o = 32; o > 0; o >>= 1) cmax = fmaxf(cmax, __shfl_xor(cmax, o));
        float nm = fmaxf(m, cmax);
        float scale = __expf(m - nm);
        denom *= scale;
        acc.x *= scale; acc.y *= scale;
        m = nm;
        float ex = valid ? __expf(alpha - m) : 0.f;
        float esum = ex;
        for (int o = 32; o > 0; o >>= 1) esum += __shfl_xor(esum, o);
        denom += esum;
        int nvalid = (re - base) < 64 ? (re - base) : 64;
        for (int t = 0; t < nvalid; t++) {
            float ext = __shfl(ex, t);
            int st = __shfl(s, t);
            float2 hv = ((const float2*)(h + (size_t)st * 128))[lane];
            acc.x += ext * hv.x;
            acc.y += ext * hv.y;
        }
    }
    float inv = 1.0f / (denom + EPS_F);
    float2 bv = ((const float2*)bias)[lane];
    float ox = acc.x * inv + bv.x;
    float oy = acc.y * inv + bv.y;
    ox = ox > 0.f ? ox : 0.f;
    oy = oy > 0.f ? oy : 0.f;
    ((float2*)(out + (size_t)i * 128))[lane] = make_float2(ox, oy);
}

// ---------------- per-node online-softmax aggregation, C=32 ----------------
__global__ void k_agg32(const float* __restrict__ h, const float* __restrict__ a_s,
                        const float* __restrict__ a_d, const float* __restrict__ ae,
                        const float* __restrict__ aesum, const int* __restrict__ cnt,
                        const int* __restrict__ offs, const int* __restrict__ csr_src,
                        const int* __restrict__ csr_eid,
                        const float* __restrict__ bias,
                        float* __restrict__ out) {
    int i = blockIdx.x;
    int lane = threadIdx.x;
    float adl = a_d[i];
    int deg = cnt[i];
    float loop_ae = aesum[i] / (float)(deg > 1 ? deg : 1);
    float al = a_s[i] + adl + loop_ae;
    al = al > 0.f ? al : al * NEG_SLOPE;
    float m = al;
    float denom = 1.0f;
    float acc = (lane < 32) ? h[(size_t)i * 32 + lane] : 0.f;
    int rs = offs[i], re = offs[i + 1];
    for (int base = rs; base < re; base += 64) {
        int el = base + lane;
        bool valid = el < re;
        float alpha = -3.4e38f;
        int s = 0;
        if (valid) {
            s = csr_src[el];
            int eid = csr_eid[el];
            float a = a_s[s] + adl + ae[eid];
            alpha = a > 0.f ? a : a * NEG_SLOPE;
        }
        float cmax = alpha;
        for (int o = 32; o > 0; o >>= 1) cmax = fmaxf(cmax, __shfl_xor(cmax, o));
        float nm = fmaxf(m, cmax);
        float scale = __expf(m - nm);
        denom *= scale;
        acc *= scale;
        m = nm;
        float ex = valid ? __expf(alpha - m) : 0.f;
        float esum = ex;
        for (int o = 32; o > 0; o >>= 1) esum += __shfl_xor(esum, o);
        denom += esum;
        int nvalid = (re - base) < 64 ? (re - base) : 64;
        for (int t = 0; t < nvalid; t++) {
            float ext = __shfl(ex, t);
            int st = __shfl(s, t);
            if (lane < 32) acc += ext * h[(size_t)st * 32 + lane];
        }
    }
    if (lane < 32) {
        float inv = 1.0f / (denom + EPS_F);
        out[(size_t)i * 32 + lane] = acc * inv + bias[lane];
    }
}

extern "C" void kernel_launch(void* const* d_in, const int* in_sizes, int n_in,
                              void* d_out, int out_size, void* d_ws, size_t ws_size,
                              hipStream_t stream) {
    const float* x    = (const float*)d_in[0];
    const int* ei     = (const int*)d_in[1];
    const float* ea   = (const float*)d_in[2];
    const float* W1   = (const float*)d_in[3];
    const float* as1v = (const float*)d_in[4];
    const float* ad1v = (const float*)d_in[5];
    const float* We1  = (const float*)d_in[6];
    const float* aev1 = (const float*)d_in[7];
    const float* b1   = (const float*)d_in[8];
    const float* W2   = (const float*)d_in[9];
    const float* as2v = (const float*)d_in[10];
    const float* ad2v = (const float*)d_in[11];
    const float* We2  = (const float*)d_in[12];
    const float* aev2 = (const float*)d_in[13];
    const float* b2   = (const float*)d_in[14];

    const int* src = ei;
    const int* dst = ei + N_EDGES;

    char* w = (char*)d_ws;
    size_t off = 0;
    auto alloc = [&](size_t bytes) -> void* {
        void* p = w + off;
        off += bytes;
        off = (off + 255) & ~(size_t)255;
        return p;
    };
    float* h1     = (float*)alloc((size_t)N_NODES * H_DIM * 4);
    float* h2     = (float*)alloc((size_t)N_NODES * O_DIM * 4);
    float* ae1    = (float*)alloc((size_t)N_EDGES * 4);
    float* ae2    = (float*)alloc((size_t)N_EDGES * 4);
    float* aesum1 = (float*)alloc((size_t)N_NODES * 4);
    float* aesum2 = (float*)alloc((size_t)N_NODES * 4);
    int* cnt      = (int*)alloc((size_t)N_NODES * 4);
    int* offs     = (int*)alloc((size_t)(N_NODES + 1) * 4);
    int* cursor   = (int*)alloc((size_t)N_NODES * 4);
    int* csr_src  = (int*)alloc((size_t)N_EDGES * 4);
    int* csr_eid  = (int*)alloc((size_t)N_EDGES * 4);
    int* bsum     = (int*)alloc(64 * 4);
    int* bpre     = (int*)alloc(64 * 4);
    float* wv1    = (float*)alloc(64 * 4);
    float* wv2    = (float*)alloc(64 * 4);
    float* a_s1   = (float*)alloc((size_t)N_NODES * 4);
    float* a_d1   = (float*)alloc((size_t)N_NODES * 4);
    float* a_s2   = (float*)alloc((size_t)N_NODES * 4);
    float* a_d2   = (float*)alloc((size_t)N_NODES * 4);
    unsigned short* W1T = (unsigned short*)alloc((size_t)H_DIM * F_DIM * 2);
    unsigned short* W2T = (unsigned short*)alloc((size_t)O_DIM * H_DIM * 2);

    hipMemsetAsync(cnt, 0, (size_t)N_NODES * 4, stream);
    hipMemsetAsync(aesum1, 0, (size_t)N_NODES * 4, stream);
    hipMemsetAsync(aesum2, 0, (size_t)N_NODES * 4, stream);

    k_wevec<<<1, 128, 0, stream>>>(We1, aev1, We2, aev2, wv1, wv2);
    k_wconv<<<32, 256, 0, stream>>>(W1, W2, W1T, W2T);
    k_edge_ae<<<4096, 256, 0, stream>>>(ea, dst, wv1, wv2, ae1, ae2, aesum1, aesum2, cnt);
    int nb = (N_NODES + 1023) / 1024;
    k_scan1<<<nb, 256, 0, stream>>>(cnt, bsum, N_NODES);
    k_scan2<<<1, 64, 0, stream>>>(bsum, bpre, offs, nb, N_NODES);
    k_scan3<<<nb, 256, 0, stream>>>(cnt, bpre, offs, N_NODES);
    hipMemcpyAsync(cursor, offs, (size_t)N_NODES * 4, hipMemcpyDeviceToDevice, stream);
    k_scatter<<<(N_EDGES + 255) / 256, 256, 0, stream>>>(src, dst, cursor, csr_src, csr_eid);

    float* out = (float*)d_out;                       // [N, O]
    float* h_out = out + (size_t)N_NODES * O_DIM;     // [N, H] = relu(x1)

    k_gemm1<<<(N_NODES + 127) / 128, 256, 0, stream>>>(x, W1T, as1v, ad1v,
                                                       h1, a_s1, a_d1, N_NODES);
    k_agg128<<<N_NODES, 64, 0, stream>>>(h1, a_s1, a_d1, ae1, aesum1, cnt,
                                         offs, csr_src, csr_eid, b1, h_out);

    k_gemm2<<<(N_NODES + 127) / 128, 256, 0, stream>>>(h_out, W2T, as2v, ad2v,
                                                       h2, a_s2, a_d2, N_NODES);
    k_agg32<<<N_NODES, 64, 0, stream>>>(h2, a_s2, a_d2, ae2, aesum2, cnt,
                                        offs, csr_src, csr_eid, b2, out);
}

// Round 6
// 409.805 us; speedup vs baseline: 1.4852x; 1.1366x over previous
//
#include <hip/hip_runtime.h>

#define N_NODES 50000
#define N_EDGES 500000
#define F_DIM 256
#define ED_DIM 64
#define H_DIM 128
#define O_DIM 32
#define NEG_SLOPE 0.2f
#define EPS_F 1e-16f
#define NEG_INF -3.4e38f

typedef __attribute__((ext_vector_type(8))) short short8;
typedef __attribute__((ext_vector_type(4))) float floatx4;

__device__ __forceinline__ unsigned short f2bf(float f) {
    union { float f; unsigned u; } c; c.f = f;
    unsigned u = c.u;
    return (unsigned short)((u + 0x7fffu + ((u >> 16) & 1u)) >> 16);
}
__device__ __forceinline__ float leaky(float a) { return a > 0.f ? a : a * NEG_SLOPE; }

// ---------------- we_vec = We @ a_edge (both layers) ----------------
__global__ void k_wevec(const float* __restrict__ We1, const float* __restrict__ aev1,
                        const float* __restrict__ We2, const float* __restrict__ aev2,
                        float* __restrict__ wv1, float* __restrict__ wv2) {
    int t = threadIdx.x;
    if (t < 64) {
        float s = 0.f;
        for (int c = 0; c < H_DIM; c++) s += We1[t * H_DIM + c] * aev1[c];
        wv1[t] = s;
    } else {
        int k = t - 64;
        float s = 0.f;
        for (int c = 0; c < O_DIM; c++) s += We2[k * O_DIM + c] * aev2[c];
        wv2[k] = s;
    }
}

// ------------- transpose+convert W1, W2 to bf16 (one-time, tiny) -------------
__global__ void k_wconv(const float* __restrict__ W1, const float* __restrict__ W2,
                        unsigned short* __restrict__ W1T, unsigned short* __restrict__ W2T) {
    int gid = blockIdx.x * blockDim.x + threadIdx.x;
    int stride = gridDim.x * blockDim.x;
    for (int i = gid; i < H_DIM * F_DIM; i += stride) {
        int n = i >> 8, k = i & 255;
        W1T[i] = f2bf(W1[k * H_DIM + n]);
    }
    for (int i = gid; i < O_DIM * H_DIM; i += stride) {
        int n = i >> 7, k = i & 127;
        W2T[i] = f2bf(W2[k * O_DIM + n]);
    }
}

// ------------- per-edge a_e, coalesced; only cnt histogram atomic -------------
__global__ __launch_bounds__(256) void k_edge_ae(const float* __restrict__ ea,
                          const int* __restrict__ dst,
                          const float* __restrict__ wv1, const float* __restrict__ wv2,
                          float* __restrict__ ae1, float* __restrict__ ae2,
                          int* __restrict__ cnt) {
    int tid = threadIdx.x;
    int wave = tid >> 6, lane = tid & 63;
    int sub = lane & 15;
    int eo = lane >> 4;
    float4 w1 = ((const float4*)wv1)[sub];
    float4 w2 = ((const float4*)wv2)[sub];
    int e0 = (blockIdx.x * 4 + wave) * 4 + eo;
    int stride = gridDim.x * 16;
    for (int e = e0; e < N_EDGES; e += stride) {
        float4 q = *(const float4*)(ea + (size_t)e * ED_DIM + sub * 4);
        float s1 = q.x * w1.x + q.y * w1.y + q.z * w1.z + q.w * w1.w;
        float s2 = q.x * w2.x + q.y * w2.y + q.z * w2.z + q.w * w2.w;
        // shfl_xor with o<16 stays inside the 16-lane subgroup (uniformly active)
#pragma unroll
        for (int o = 1; o < 16; o <<= 1) {
            s1 += __shfl_xor(s1, o);
            s2 += __shfl_xor(s2, o);
        }
        if (sub == 0) {
            ae1[e] = s1; ae2[e] = s2;
            atomicAdd(&cnt[dst[e]], 1);
        }
    }
}

// ---------------- prefix-sum (CSR offsets) ----------------
__global__ void k_scan1(const int* __restrict__ cnt, int* __restrict__ bsum, int n) {
    __shared__ int sh[256];
    int b = blockIdx.x, t = threadIdx.x;
    int base = b * 1024;
    int s = 0;
    for (int j = 0; j < 4; j++) {
        int idx = base + t * 4 + j;
        if (idx < n) s += cnt[idx];
    }
    sh[t] = s; __syncthreads();
    for (int o = 128; o > 0; o >>= 1) {
        if (t < o) sh[t] += sh[t + o];
        __syncthreads();
    }
    if (t == 0) bsum[b] = sh[0];
}

__global__ void k_scan2(const int* __restrict__ bsum, int* __restrict__ bpre,
                        int* __restrict__ offs, int nb, int n) {
    if (threadIdx.x == 0) {
        int run = 0;
        for (int b = 0; b < nb; b++) { bpre[b] = run; run += bsum[b]; }
        offs[n] = run;
    }
}

__global__ void k_scan3(const int* __restrict__ cnt, const int* __restrict__ bpre,
                        int* __restrict__ offs, int n) {
    __shared__ int sh[256];
    int b = blockIdx.x, t = threadIdx.x;
    int base = b * 1024;
    int v[4]; int s = 0;
    for (int j = 0; j < 4; j++) {
        int idx = base + t * 4 + j;
        v[j] = (idx < n) ? cnt[idx] : 0;
        s += v[j];
    }
    sh[t] = s; __syncthreads();
    for (int o = 1; o < 256; o <<= 1) {
        int x = (t >= o) ? sh[t - o] : 0;
        __syncthreads();
        sh[t] += x;
        __syncthreads();
    }
    int texcl = sh[t] - s + bpre[b];
    int run = 0;
    for (int j = 0; j < 4; j++) {
        int idx = base + t * 4 + j;
        if (idx < n) offs[idx] = texcl + run;
        run += v[j];
    }
}

// scatter edges into CSR order; also deposit ae values
__global__ void k_scatter(const int* __restrict__ src, const int* __restrict__ dst,
                          const float* __restrict__ ae1, const float* __restrict__ ae2,
                          int* __restrict__ cursor,
                          int* __restrict__ csr_src,
                          float* __restrict__ csr_ae1, float* __restrict__ csr_ae2) {
    int e = blockIdx.x * blockDim.x + threadIdx.x;
    if (e >= N_EDGES) return;
    int d = dst[e];
    int p = atomicAdd(&cursor[d], 1);
    csr_src[p] = src[e];
    csr_ae1[p] = ae1[e];
    csr_ae2[p] = ae2[e];
}

// =============== MFMA GEMM layer 1: h1 = x@W1, fused a_s/a_d ===============
__global__ __launch_bounds__(256) void k_gemm1(const float* __restrict__ A,
        const unsigned short* __restrict__ BT,
        const float* __restrict__ asv, const float* __restrict__ adv,
        float* __restrict__ C, float* __restrict__ a_s, float* __restrict__ a_d, int M) {
    __shared__ unsigned short As[128 * 40];
    __shared__ unsigned short Bs[128 * 40];
    int tid = threadIdx.x;
    int wave = tid >> 6, lane = tid & 63;
    int q = lane >> 4, r = lane & 15;
    int bm0 = blockIdx.x * 128;
    floatx4 acc[2][8];
#pragma unroll
    for (int a = 0; a < 2; a++)
#pragma unroll
        for (int b = 0; b < 8; b++) acc[a][b] = (floatx4){0.f, 0.f, 0.f, 0.f};

    int rr = tid >> 3;
    int kc = tid & 7;
    for (int k0 = 0; k0 < 256; k0 += 32) {
#pragma unroll
        for (int i = 0; i < 4; i++) {
            int row = rr + 32 * i;
            int gr = bm0 + row;
            float4 v = make_float4(0.f, 0.f, 0.f, 0.f);
            if (gr < M) v = *(const float4*)(A + (size_t)gr * 256 + k0 + kc * 4);
            unsigned lo = (unsigned)f2bf(v.x) | ((unsigned)f2bf(v.y) << 16);
            unsigned hi = (unsigned)f2bf(v.z) | ((unsigned)f2bf(v.w) << 16);
            *(uint2*)&As[row * 40 + kc * 4] = make_uint2(lo, hi);
        }
#pragma unroll
        for (int i = 0; i < 2; i++) {
            int idx = tid + 256 * i;
            int n = idx >> 2, ck = idx & 3;
            *(uint4*)&Bs[n * 40 + ck * 8] = *(const uint4*)(BT + n * 256 + k0 + ck * 8);
        }
        __syncthreads();
        short8 af[2], bf[8];
#pragma unroll
        for (int rt = 0; rt < 2; rt++)
            af[rt] = *(const short8*)&As[(wave * 32 + rt * 16 + r) * 40 + q * 8];
#pragma unroll
        for (int nt = 0; nt < 8; nt++)
            bf[nt] = *(const short8*)&Bs[(nt * 16 + r) * 40 + q * 8];
#pragma unroll
        for (int rt = 0; rt < 2; rt++)
#pragma unroll
            for (int nt = 0; nt < 8; nt++)
                acc[rt][nt] = __builtin_amdgcn_mfma_f32_16x16x32_bf16(af[rt], bf[nt], acc[rt][nt], 0, 0, 0);
        __syncthreads();
    }
#pragma unroll
    for (int rt = 0; rt < 2; rt++) {
        int rowb = bm0 + wave * 32 + rt * 16 + q * 4;
        float ps[4] = {0.f, 0.f, 0.f, 0.f}, pd[4] = {0.f, 0.f, 0.f, 0.f};
#pragma unroll
        for (int nt = 0; nt < 8; nt++) {
            int col = nt * 16 + r;
            float av = asv[col], dv = adv[col];
#pragma unroll
            for (int reg = 0; reg < 4; reg++) {
                float v = acc[rt][nt][reg];
                if (rowb + reg < M) C[(size_t)(rowb + reg) * 128 + col] = v;
                ps[reg] += v * av;
                pd[reg] += v * dv;
            }
        }
#pragma unroll
        for (int reg = 0; reg < 4; reg++) {
#pragma unroll
            for (int off = 1; off < 16; off <<= 1) {
                ps[reg] += __shfl_xor(ps[reg], off);
                pd[reg] += __shfl_xor(pd[reg], off);
            }
        }
        if (r == 0) {
#pragma unroll
            for (int reg = 0; reg < 4; reg++) {
                if (rowb + reg < M) { a_s[rowb + reg] = ps[reg]; a_d[rowb + reg] = pd[reg]; }
            }
        }
    }
}

// =============== MFMA GEMM layer 2: h2 = relu(x1)@W2, fused a_s/a_d ===============
__global__ __launch_bounds__(256) void k_gemm2(const float* __restrict__ A,
        const unsigned short* __restrict__ BT,
        const float* __restrict__ asv, const float* __restrict__ adv,
        float* __restrict__ C, float* __restrict__ a_s, float* __restrict__ a_d, int M) {
    __shared__ unsigned short As[128 * 40];
    __shared__ unsigned short Bs[32 * 40];
    int tid = threadIdx.x;
    int wave = tid >> 6, lane = tid & 63;
    int q = lane >> 4, r = lane & 15;
    int bm0 = blockIdx.x * 128;
    floatx4 acc[2][2];
#pragma unroll
    for (int a = 0; a < 2; a++)
#pragma unroll
        for (int b = 0; b < 2; b++) acc[a][b] = (floatx4){0.f, 0.f, 0.f, 0.f};

    int rr = tid >> 3;
    int kc = tid & 7;
    for (int k0 = 0; k0 < 128; k0 += 32) {
#pragma unroll
        for (int i = 0; i < 4; i++) {
            int row = rr + 32 * i;
            int gr = bm0 + row;
            float4 v = make_float4(0.f, 0.f, 0.f, 0.f);
            if (gr < M) v = *(const float4*)(A + (size_t)gr * 128 + k0 + kc * 4);
            unsigned lo = (unsigned)f2bf(v.x) | ((unsigned)f2bf(v.y) << 16);
            unsigned hi = (unsigned)f2bf(v.z) | ((unsigned)f2bf(v.w) << 16);
            *(uint2*)&As[row * 40 + kc * 4] = make_uint2(lo, hi);
        }
        if (tid < 128) {
            int n = tid >> 2, ck = tid & 3;
            *(uint4*)&Bs[n * 40 + ck * 8] = *(const uint4*)(BT + n * 128 + k0 + ck * 8);
        }
        __syncthreads();
        short8 af[2], bf[2];
#pragma unroll
        for (int rt = 0; rt < 2; rt++)
            af[rt] = *(const short8*)&As[(wave * 32 + rt * 16 + r) * 40 + q * 8];
#pragma unroll
        for (int nt = 0; nt < 2; nt++)
            bf[nt] = *(const short8*)&Bs[(nt * 16 + r) * 40 + q * 8];
#pragma unroll
        for (int rt = 0; rt < 2; rt++)
#pragma unroll
            for (int nt = 0; nt < 2; nt++)
                acc[rt][nt] = __builtin_amdgcn_mfma_f32_16x16x32_bf16(af[rt], bf[nt], acc[rt][nt], 0, 0, 0);
        __syncthreads();
    }
#pragma unroll
    for (int rt = 0; rt < 2; rt++) {
        int rowb = bm0 + wave * 32 + rt * 16 + q * 4;
        float ps[4] = {0.f, 0.f, 0.f, 0.f}, pd[4] = {0.f, 0.f, 0.f, 0.f};
#pragma unroll
        for (int nt = 0; nt < 2; nt++) {
            int col = nt * 16 + r;
            float av = asv[col], dv = adv[col];
#pragma unroll
            for (int reg = 0; reg < 4; reg++) {
                float v = acc[rt][nt][reg];
                if (rowb + reg < M) C[(size_t)(rowb + reg) * 32 + col] = v;
                ps[reg] += v * av;
                pd[reg] += v * dv;
            }
        }
#pragma unroll
        for (int reg = 0; reg < 4; reg++) {
#pragma unroll
            for (int off = 1; off < 16; off <<= 1) {
                ps[reg] += __shfl_xor(ps[reg], off);
                pd[reg] += __shfl_xor(pd[reg], off);
            }
        }
        if (r == 0) {
#pragma unroll
            for (int reg = 0; reg < 4; reg++) {
                if (rowb + reg < M) { a_s[rowb + reg] = ps[reg]; a_d[rowb + reg] = pd[reg]; }
            }
        }
    }
}

// ========== per-node exact-softmax aggregation, C=128 (4 waves = 4 nodes/block) ==========
template <bool RELU>
__global__ __launch_bounds__(256) void k_agg128(const float* __restrict__ h,
                         const float* __restrict__ a_s, const float* __restrict__ a_d,
                         const int* __restrict__ offs, const int* __restrict__ csr_src,
                         const float* __restrict__ csr_ae,
                         const float* __restrict__ bias,
                         float* __restrict__ out) {
    int wave = threadIdx.x >> 6, lane = threadIdx.x & 63;
    int i = blockIdx.x * 4 + wave;
    int r = lane & 15;       // channel group: channels r*8 .. r*8+7
    int g = lane >> 4;       // edge subgroup
    int rs = offs[i], re = offs[i + 1];
    int deg = re - rs;
    float adl = a_d[i];
    // ---- pass A: sum of ae (self-loop mean) + max alpha ----
    float sum_ae = 0.f, amax = NEG_INF;
    for (int el = rs + lane; el < re; el += 64) {
        float aev = csr_ae[el];
        float a = leaky(a_s[csr_src[el]] + adl + aev);
        sum_ae += aev;
        amax = fmaxf(amax, a);
    }
#pragma unroll
    for (int o = 32; o > 0; o >>= 1) {
        sum_ae += __shfl_xor(sum_ae, o);
        amax = fmaxf(amax, __shfl_xor(amax, o));
    }
    float loop_ae = sum_ae / (float)(deg > 1 ? deg : 1);
    float al = leaky(a_s[i] + adl + loop_ae);
    float m = fmaxf(amax, al);
    float exs = __expf(al - m);
    // ---- pass B: exp + 4-edges-in-flight gather (WAVE-UNIFORM shfl loop!) ----
    float4 acc0 = {0.f, 0.f, 0.f, 0.f}, acc1 = {0.f, 0.f, 0.f, 0.f};
    float dsum = 0.f;
    for (int base = rs; base < re; base += 64) {
        int el = base + lane;
        float ex = 0.f; int s = 0;
        if (el < re) {
            s = csr_src[el];
            float a = leaky(a_s[s] + adl + csr_ae[el]);
            ex = __expf(a - m);
        }
        dsum += ex;
        int nv = (re - base) < 64 ? (re - base) : 64;
        int kmax = (nv + 3) >> 2;          // wave-uniform trip count
        for (int k = 0; k < kmax; k++) {
            int t = g + 4 * k;             // t <= 63 always
            // shfl executed by ALL lanes (uniform loop) -> source lanes active
            float ext = __shfl(ex, t);
            int st = __shfl(s, t);
            if (t < nv) {                  // predicate only the load/FMA
                const float4* hr = (const float4*)(h + (size_t)st * 128);
                float4 v0 = hr[r * 2], v1 = hr[r * 2 + 1];
                acc0.x += ext * v0.x; acc0.y += ext * v0.y; acc0.z += ext * v0.z; acc0.w += ext * v0.w;
                acc1.x += ext * v1.x; acc1.y += ext * v1.y; acc1.z += ext * v1.z; acc1.w += ext * v1.w;
            }
        }
    }
#pragma unroll
    for (int o = 32; o > 0; o >>= 1) dsum += __shfl_xor(dsum, o);
    float* a0 = (float*)&acc0; float* a1 = (float*)&acc1;
#pragma unroll
    for (int c = 0; c < 4; c++) {
        a0[c] += __shfl_xor(a0[c], 16); a0[c] += __shfl_xor(a0[c], 32);
        a1[c] += __shfl_xor(a1[c], 16); a1[c] += __shfl_xor(a1[c], 32);
    }
    if (g == 0) {
        float denom = dsum + exs;
        float inv = 1.0f / (denom + EPS_F);
        const float4* hr = (const float4*)(h + (size_t)i * 128);
        float4 h0 = hr[r * 2], h1 = hr[r * 2 + 1];
        const float4* bp = (const float4*)bias;
        float4 b0 = bp[r * 2], b1 = bp[r * 2 + 1];
        float4 o0, o1;
        o0.x = (a0[0] + exs * h0.x) * inv + b0.x;
        o0.y = (a0[1] + exs * h0.y) * inv + b0.y;
        o0.z = (a0[2] + exs * h0.z) * inv + b0.z;
        o0.w = (a0[3] + exs * h0.w) * inv + b0.w;
        o1.x = (a1[0] + exs * h1.x) * inv + b1.x;
        o1.y = (a1[1] + exs * h1.y) * inv + b1.y;
        o1.z = (a1[2] + exs * h1.z) * inv + b1.z;
        o1.w = (a1[3] + exs * h1.w) * inv + b1.w;
        if (RELU) {
            o0.x = fmaxf(o0.x, 0.f); o0.y = fmaxf(o0.y, 0.f); o0.z = fmaxf(o0.z, 0.f); o0.w = fmaxf(o0.w, 0.f);
            o1.x = fmaxf(o1.x, 0.f); o1.y = fmaxf(o1.y, 0.f); o1.z = fmaxf(o1.z, 0.f); o1.w = fmaxf(o1.w, 0.f);
        }
        float4* op = (float4*)(out + (size_t)i * 128);
        op[r * 2] = o0;
        op[r * 2 + 1] = o1;
    }
}

// ========== per-node exact-softmax aggregation, C=32 (4 waves = 4 nodes/block) ==========
__global__ __launch_bounds__(256) void k_agg32(const float* __restrict__ h,
                        const float* __restrict__ a_s, const float* __restrict__ a_d,
                        const int* __restrict__ offs, const int* __restrict__ csr_src,
                        const float* __restrict__ csr_ae,
                        const float* __restrict__ bias,
                        float* __restrict__ out) {
    int wave = threadIdx.x >> 6, lane = threadIdx.x & 63;
    int i = blockIdx.x * 4 + wave;
    int r = lane & 15;       // channels r*2, r*2+1
    int g = lane >> 4;
    int rs = offs[i], re = offs[i + 1];
    int deg = re - rs;
    float adl = a_d[i];
    float sum_ae = 0.f, amax = NEG_INF;
    for (int el = rs + lane; el < re; el += 64) {
        float aev = csr_ae[el];
        float a = leaky(a_s[csr_src[el]] + adl + aev);
        sum_ae += aev;
        amax = fmaxf(amax, a);
    }
#pragma unroll
    for (int o = 32; o > 0; o >>= 1) {
        sum_ae += __shfl_xor(sum_ae, o);
        amax = fmaxf(amax, __shfl_xor(amax, o));
    }
    float loop_ae = sum_ae / (float)(deg > 1 ? deg : 1);
    float al = leaky(a_s[i] + adl + loop_ae);
    float m = fmaxf(amax, al);
    float exs = __expf(al - m);
    float2 acc = {0.f, 0.f};
    float dsum = 0.f;
    for (int base = rs; base < re; base += 64) {
        int el = base + lane;
        float ex = 0.f; int s = 0;
        if (el < re) {
            s = csr_src[el];
            float a = leaky(a_s[s] + adl + csr_ae[el]);
            ex = __expf(a - m);
        }
        dsum += ex;
        int nv = (re - base) < 64 ? (re - base) : 64;
        int kmax = (nv + 3) >> 2;          // wave-uniform trip count
        for (int k = 0; k < kmax; k++) {
            int t = g + 4 * k;
            float ext = __shfl(ex, t);
            int st = __shfl(s, t);
            if (t < nv) {
                float2 v = ((const float2*)(h + (size_t)st * 32))[r];
                acc.x += ext * v.x; acc.y += ext * v.y;
            }
        }
    }
#pragma unroll
    for (int o = 32; o > 0; o >>= 1) dsum += __shfl_xor(dsum, o);
    acc.x += __shfl_xor(acc.x, 16); acc.x += __shfl_xor(acc.x, 32);
    acc.y += __shfl_xor(acc.y, 16); acc.y += __shfl_xor(acc.y, 32);
    if (g == 0) {
        float denom = dsum + exs;
        float inv = 1.0f / (denom + EPS_F);
        float2 hv = ((const float2*)(h + (size_t)i * 32))[r];
        float2 bv = ((const float2*)bias)[r];
        float2 ov;
        ov.x = (acc.x + exs * hv.x) * inv + bv.x;
        ov.y = (acc.y + exs * hv.y) * inv + bv.y;
        ((float2*)(out + (size_t)i * 32))[r] = ov;
    }
}

extern "C" void kernel_launch(void* const* d_in, const int* in_sizes, int n_in,
                              void* d_out, int out_size, void* d_ws, size_t ws_size,
                              hipStream_t stream) {
    const float* x    = (const float*)d_in[0];
    const int* ei     = (const int*)d_in[1];
    const float* ea   = (const float*)d_in[2];
    const float* W1   = (const float*)d_in[3];
    const float* as1v = (const float*)d_in[4];
    const float* ad1v = (const float*)d_in[5];
    const float* We1  = (const float*)d_in[6];
    const float* aev1 = (const float*)d_in[7];
    const float* b1   = (const float*)d_in[8];
    const float* W2   = (const float*)d_in[9];
    const float* as2v = (const float*)d_in[10];
    const float* ad2v = (const float*)d_in[11];
    const float* We2  = (const float*)d_in[12];
    const float* aev2 = (const float*)d_in[13];
    const float* b2   = (const float*)d_in[14];

    const int* src = ei;
    const int* dst = ei + N_EDGES;

    char* w = (char*)d_ws;
    size_t off = 0;
    auto alloc = [&](size_t bytes) -> void* {
        void* p = w + off;
        off += bytes;
        off = (off + 255) & ~(size_t)255;
        return p;
    };
    float* h1      = (float*)alloc((size_t)N_NODES * H_DIM * 4);
    float* h2      = (float*)alloc((size_t)N_NODES * O_DIM * 4);
    float* ae1     = (float*)alloc((size_t)N_EDGES * 4);
    float* ae2     = (float*)alloc((size_t)N_EDGES * 4);
    int* cnt       = (int*)alloc((size_t)N_NODES * 4);
    int* offs      = (int*)alloc((size_t)(N_NODES + 1) * 4);
    int* cursor    = (int*)alloc((size_t)N_NODES * 4);
    int* csr_src   = (int*)alloc((size_t)N_EDGES * 4);
    float* csr_ae1 = (float*)alloc((size_t)N_EDGES * 4);
    float* csr_ae2 = (float*)alloc((size_t)N_EDGES * 4);
    int* bsum      = (int*)alloc(64 * 4);
    int* bpre      = (int*)alloc(64 * 4);
    float* wv1     = (float*)alloc(64 * 4);
    float* wv2     = (float*)alloc(64 * 4);
    float* a_s1    = (float*)alloc((size_t)N_NODES * 4);
    float* a_d1    = (float*)alloc((size_t)N_NODES * 4);
    float* a_s2    = (float*)alloc((size_t)N_NODES * 4);
    float* a_d2    = (float*)alloc((size_t)N_NODES * 4);
    unsigned short* W1T = (unsigned short*)alloc((size_t)H_DIM * F_DIM * 2);
    unsigned short* W2T = (unsigned short*)alloc((size_t)O_DIM * H_DIM * 2);

    hipMemsetAsync(cnt, 0, (size_t)N_NODES * 4, stream);

    k_wevec<<<1, 128, 0, stream>>>(We1, aev1, We2, aev2, wv1, wv2);
    k_wconv<<<32, 256, 0, stream>>>(W1, W2, W1T, W2T);
    k_edge_ae<<<4096, 256, 0, stream>>>(ea, dst, wv1, wv2, ae1, ae2, cnt);
    int nb = (N_NODES + 1023) / 1024;
    k_scan1<<<nb, 256, 0, stream>>>(cnt, bsum, N_NODES);
    k_scan2<<<1, 64, 0, stream>>>(bsum, bpre, offs, nb, N_NODES);
    k_scan3<<<nb, 256, 0, stream>>>(cnt, bpre, offs, N_NODES);
    hipMemcpyAsync(cursor, offs, (size_t)N_NODES * 4, hipMemcpyDeviceToDevice, stream);
    k_scatter<<<(N_EDGES + 255) / 256, 256, 0, stream>>>(src, dst, ae1, ae2, cursor,
                                                         csr_src, csr_ae1, csr_ae2);

    float* out = (float*)d_out;                       // [N, O]
    float* h_out = out + (size_t)N_NODES * O_DIM;     // [N, H] = relu(x1)

    k_gemm1<<<(N_NODES + 127) / 128, 256, 0, stream>>>(x, W1T, as1v, ad1v,
                                                       h1, a_s1, a_d1, N_NODES);
    k_agg128<true><<<(N_NODES + 3) / 4, 256, 0, stream>>>(h1, a_s1, a_d1, offs,
                                                          csr_src, csr_ae1, b1, h_out);

    k_gemm2<<<(N_NODES + 127) / 128, 256, 0, stream>>>(h_out, W2T, as2v, ad2v,
                                                       h2, a_s2, a_d2, N_NODES);
    k_agg32<<<(N_NODES + 3) / 4, 256, 0, stream>>>(h2, a_s2, a_d2, offs,
                                                   csr_src, csr_ae2, b2, out);
}